// Round 10
// baseline (152.592 us; speedup 1.0000x reference)
//
#include <hip/hip_runtime.h>

// Match numpy f32 semantics: no FMA contraction anywhere in this TU.
#pragma clang fp contract(off)

#define VWD 96
#define NVERT 2048
#define NFAC 512
#define NBATCH 8
#define NSLAB 3456          // 12 x 12 x 24 slabs of 8x8x4 voxels
#define RECF 20             // floats per facet body record (AoS, scalar-loaded)
#define CULC 22             // cull components (SoA): bbox 6 + 4 planes x 4

// SoA cull addressing: component c, batch b, facet f
#define CUL(c, b, f) cul[(size_t)(c) * (NBATCH * NFAC) + (size_t)(b) * NFAC + (f)]

// ---------------------------------------------------------------------------
// Kernel 1: per-batch facet precompute, ordered by |det| descending via a
// ONE-BARRIER rank sort. Fully scalarized (no local arrays). Body records
// SIGN-FOLDED: det<0 => negate A,det (IEEE negation commutes exactly through
// mul/add/div, so n'/det' == n/det bit-for-bit).
// ---------------------------------------------------------------------------
__global__ __launch_bounds__(512) void precompute_kernel(
    const float* __restrict__ vertices,
    const int*   __restrict__ facets,
    float*       __restrict__ cul,
    float*       __restrict__ body)
{
    __shared__ unsigned skey[NFAC];
    const int b = blockIdx.x;
    const int j = threadIdx.x;          // one facet per thread
    const float* vb = vertices + (size_t)b * NVERT * 3;

    int4 fi = ((const int4*)facets)[b * NFAC + j];
    float x0 = vb[3*fi.x+0], y0 = vb[3*fi.x+1], z0 = vb[3*fi.x+2];
    float x1 = vb[3*fi.y+0], y1 = vb[3*fi.y+1], z1 = vb[3*fi.y+2];
    float x2 = vb[3*fi.z+0], y2 = vb[3*fi.z+1], z2 = vb[3*fi.z+2];
    float x3 = vb[3*fi.w+0], y3 = vb[3*fi.w+1], z3 = vb[3*fi.w+2];
    float a  = x0-x3, bb = x1-x3, c  = x2-x3;
    float d  = y0-y3, e  = y1-y3, f  = y2-y3;
    float g  = z0-z3, h  = z1-z3, ii = z2-z3;
    float A00 = e*ii - f*h,  A01 = c*h  - bb*ii, A02 = bb*f - c*e;
    float A10 = f*g  - d*ii, A11 = a*ii - c*g,   A12 = c*d  - a*f;
    float A20 = d*h  - e*g,  A21 = bb*g - a*h,   A22 = a*e  - bb*d;
    float det = a*(e*ii - f*h) - bb*(d*ii - f*g) + c*(d*h - e*g);
    if (det < 0.0f) {   // sign-fold (exact)
        det = -det;
        A00 = -A00; A01 = -A01; A02 = -A02;
        A10 = -A10; A11 = -A11; A12 = -A12;
        A20 = -A20; A21 = -A21; A22 = -A22;
    }
    unsigned myk = ~__float_as_uint(det);   // ascending key == descending |det|
    skey[j] = myk;
    __syncthreads();

    // rank = #{k : key_k < myk or (key_k == myk and k < j)}  -> unique slot
    int rank = 0;
    const uint4* sk4 = (const uint4*)skey;
    for (int k0 = 0; k0 < NFAC; k0 += 4) {
        uint4 kk = sk4[k0 >> 2];
        rank += (kk.x < myk) + ((kk.x == myk) & (k0 + 0 < j));
        rank += (kk.y < myk) + ((kk.y == myk) & (k0 + 1 < j));
        rank += (kk.z < myk) + ((kk.z == myk) & (k0 + 2 < j));
        rank += (kk.w < myk) + ((kk.w == myk) & (k0 + 3 < j));
    }

    CUL(0, b, rank) = fminf(fminf(x0,x1),fminf(x2,x3)) - 1e-4f;
    CUL(1, b, rank) = fminf(fminf(y0,y1),fminf(y2,y3)) - 1e-4f;
    CUL(2, b, rank) = fminf(fminf(z0,z1),fminf(z2,z3)) - 1e-4f;
    CUL(3, b, rank) = fmaxf(fmaxf(x0,x1),fmaxf(x2,x3)) + 1e-4f;
    CUL(4, b, rank) = fmaxf(fmaxf(y0,y1),fmaxf(y2,y3)) + 1e-4f;
    CUL(5, b, rank) = fmaxf(fmaxf(z0,z1),fmaxf(z2,z3)) + 1e-4f;

    // 4 outward face planes, margin-inflated, slab half-extents folded:
    // mask test becomes  dot(n, slab_center) <= rhs  (conservative).
    const float HX = 7.0f/96.0f, HZ = 3.0f/96.0f;
    auto plane = [&](float pax, float pay, float paz,
                     float pbx, float pby, float pbz,
                     float pcx, float pcy, float pcz,
                     float pox, float poy, float poz, int base) {
        float e1x = pbx-pax, e1y = pby-pay, e1z = pbz-paz;
        float e2x = pcx-pax, e2y = pcy-pay, e2z = pcz-paz;
        float nx = e1y*e2z - e1z*e2y;
        float ny = e1z*e2x - e1x*e2z;
        float nz = e1x*e2y - e1y*e2x;
        float sdot = nx*(pox-pax) + ny*(poy-pay) + nz*(poz-paz);
        if (sdot > 0.0f) { nx=-nx; ny=-ny; nz=-nz; sdot=-sdot; }
        float dpl = nx*pax + ny*pay + nz*paz;
        float n1s = fabsf(nx)+fabsf(ny)+fabsf(nz);
        float M = 1e-4f*(-sdot) + 1e-4f*n1s + 1e-4f;
        float rhs = dpl + M + (fabsf(nx)*HX + fabsf(ny)*HX + fabsf(nz)*HZ);
        CUL(base+0, b, rank) = nx;
        CUL(base+1, b, rank) = ny;
        CUL(base+2, b, rank) = nz;
        CUL(base+3, b, rank) = rhs;
    };
    plane(x1,y1,z1, x2,y2,z2, x3,y3,z3, x0,y0,z0, 6);    // opposite v0
    plane(x0,y0,z0, x2,y2,z2, x3,y3,z3, x1,y1,z1, 10);   // opposite v1
    plane(x0,y0,z0, x1,y1,z1, x3,y3,z3, x2,y2,z2, 14);   // opposite v2
    plane(x0,y0,z0, x1,y1,z1, x2,y2,z2, x3,y3,z3, 18);   // opposite v3

    const float DZ = 2.0f / 96.0f;
    float margA = det * 1e-4f + 1e-3f;
    float* bo = body + ((size_t)b * NFAC + rank) * RECF;
    bo[0]  = det; bo[1]  = x3;  bo[2]  = y3;  bo[3]  = z3;
    bo[4]  = A00; bo[5]  = A01; bo[6]  = A02;
    bo[7]  = A10; bo[8]  = A11; bo[9]  = A12;
    bo[10] = A20; bo[11] = A21; bo[12] = A22;
    bo[13] = margA;
    bo[14] = det - margA;          // dhi  (definite upper)
    bo[15] = det + margA;          // mhi  (maybe upper)
    float ss0 = A02 * DZ, ss1 = A12 * DZ, ss2 = A22 * DZ;
    bo[16] = ss0; bo[17] = ss1; bo[18] = ss2;
    bo[19] = ss0 + ss1 + ss2;      // sss
}

// ---------------------------------------------------------------------------
// Kernel 2: per-slab 512-bit facet mask. One block per (batch, x-y column);
// facet-per-lane, cull record loaded ONCE (SoA, coalesced), 24 z-slabs via
// incremental plane dots (error ~3e-6 << 1e-4 margin folded into rhs).
// ---------------------------------------------------------------------------
__global__ __launch_bounds__(512) void mask_kernel(
    const float* __restrict__ cul,
    unsigned long long* __restrict__ masks)
{
    const int col = blockIdx.x;           // 0..143 = sx*12+sy
    const int b   = blockIdx.y;
    const int f   = threadIdx.x;          // facet (sorted order)
    const int w   = threadIdx.x >> 6;
    float bminx=CUL(0,b,f), bminy=CUL(1,b,f), bminz=CUL(2,b,f);
    float bmaxx=CUL(3,b,f), bmaxy=CUL(4,b,f), bmaxz=CUL(5,b,f);
    float n0x=CUL(6,b,f),  n0y=CUL(7,b,f),  n0z=CUL(8,b,f),  r0=CUL(9,b,f);
    float n1x=CUL(10,b,f), n1y=CUL(11,b,f), n1z=CUL(12,b,f), r1=CUL(13,b,f);
    float n2x=CUL(14,b,f), n2y=CUL(15,b,f), n2z=CUL(16,b,f), r2=CUL(17,b,f);
    float n3x=CUL(18,b,f), n3y=CUL(19,b,f), n3z=CUL(20,b,f), r3=CUL(21,b,f);

    const int sx = col / 12, sy = col % 12;
    const float cx = (float)(16*sx + 8 - VWD) / 96.0f;
    const float cy = (float)(16*sy + 8 - VWD) / 96.0f;
    const float colminx = (float)(16*sx + 1  - VWD) / 96.0f;
    const float colmaxx = (float)(16*sx + 15 - VWD) / 96.0f;
    const float colminy = (float)(16*sy + 1  - VWD) / 96.0f;
    const float colmaxy = (float)(16*sy + 15 - VWD) / 96.0f;
    const bool ovxy = (bminx <= colmaxx) & (bmaxx >= colminx) &
                      (bminy <= colmaxy) & (bmaxy >= colminy);

    const float cz0   = (float)(4 - VWD) / 96.0f;   // z-center of slab sz=0
    const float stepc = 8.0f / 96.0f;
    float d0 = n0x*cx + n0y*cy + n0z*cz0 - r0;  float s0 = n0z*stepc;
    float d1 = n1x*cx + n1y*cy + n1z*cz0 - r1;  float s1 = n1z*stepc;
    float d2 = n2x*cx + n2y*cy + n2z*cz0 - r2;  float s2 = n2z*stepc;
    float d3 = n3x*cx + n3y*cy + n3z*cz0 - r3;  float s3 = n3z*stepc;
    float zlo = (float)(1 - VWD) / 96.0f;
    float zhi = (float)(7 - VWD) / 96.0f;

    unsigned long long* mp = masks + ((size_t)b * NSLAB + (size_t)col * 24) * 8 + w;
#pragma unroll 4
    for (int sz = 0; sz < 24; ++sz) {
        bool ov = ovxy & (bminz <= zhi) & (bmaxz >= zlo) &
                  (d0 <= 0.0f) & (d1 <= 0.0f) & (d2 <= 0.0f) & (d3 <= 0.0f);
        unsigned long long bal = __ballot((int)ov);
        if ((threadIdx.x & 63) == 0) mp[(size_t)sz * 8] = bal;
        d0 += s0; d1 += s1; d2 += s2; d3 += s3;
        zlo += stepc; zhi += stepc;
    }
}

// ---------------------------------------------------------------------------
// Kernel 3: one wave per 8x8x4 slab (4 z-voxels/lane), slab index SWIZZLED
// (coprime stride) so heavy shell slabs spread across the dispatch tail.
// Candidate loop processes TWO facets per iteration: both 20-float records
// loaded unconditionally (straight-line, stays in SGPRs), so the second's
// s_load latency hides under the first's VALU. Exact ref path only for the
// ~1e-3 uncertainty shell.
// ---------------------------------------------------------------------------
__global__ __launch_bounds__(256) void voxelize_kernel(
    const float*              __restrict__ body,
    const unsigned long long* __restrict__ masks,
    float*                    __restrict__ out)
{
    const int b    = blockIdx.y;
    const int wave = threadIdx.x >> 6;
    const int lane = threadIdx.x & 63;
    const int raw  = blockIdx.x * 4 + wave;          // 0 .. 3455
    const int slab = (raw * 1537) % NSLAB;           // coprime swizzle
    const int sz = slab % 24;
    const int sy = (slab / 24) % 12;
    const int sx = slab / 288;
    const int ix  = sx*8 + (lane >> 3);
    const int iy  = sy*8 + (lane & 7);
    const int iz0 = sz*4;

    const float px  = (float)(2*ix  + 1 - VWD) / 96.0f;
    const float py  = (float)(2*iy  + 1 - VWD) / 96.0f;
    const float pz0 = (float)(2*iz0 + 1 - VWD) / 96.0f;

    const unsigned long long* mp = masks + ((size_t)b * NSLAB + slab) * 8;
    const float* bb = body + (size_t)b * NFAC * RECF;

    unsigned fnd = 0u;   // bit k = voxel (ix,iy,iz0+k) found

    // process one facet record (by pointer; fields resolve to s_loads)
    auto process = [&](const float* __restrict__ bo) {
        float det = bo[0], v3x = bo[1], v3y = bo[2], v3z = bo[3];
        float A00 = bo[4],  A01 = bo[5],  A02 = bo[6];
        float A10 = bo[7],  A11 = bo[8],  A12 = bo[9];
        float A20 = bo[10], A21 = bo[11], A22 = bo[12];
        float margA = bo[13], dhi = bo[14], mhi = bo[15];
        float ss0 = bo[16], ss1 = bo[17], ss2 = bo[18], sss = bo[19];
        float dx = px - v3x, dy = py - v3y, dz0 = pz0 - v3z;
        // ref-exact at k=0 (left-assoc)
        float n0 = A00*dx + A01*dy + A02*dz0;
        float n1 = A10*dx + A11*dy + A12*dz0;
        float n2 = A20*dx + A21*dy + A22*dz0;
        float sm = n0 + n1 + n2;
        float nmargA = -margA;
#pragma unroll
        for (int k = 0; k < 4; ++k) {
            float mn = fminf(fminf(n0, n1), n2);   // v_min3_f32
            // definite: rigorously implies ref-inside (no divisions)
            bool def = (mn >= margA) & (sm <= dhi);
            // maybe: rigorously implied by ref-inside
            bool may = (mn >= nmargA) & (sm <= mhi);
            bool needex = may & !def & !((fnd >> k) & 1u);
            if (__any(needex)) {
                // exact path: op-identical to reference (sign-folding
                // commutes exactly through IEEE mul/add/div)
                int izk = iz0 + k;
                float pzk = (float)(2*izk + 1 - VWD) / 96.0f;
                float dzk = pzk - v3z;
                float e0 = A00*dx + A01*dy + A02*dzk;
                float e1 = A10*dx + A11*dy + A12*dzk;
                float e2 = A20*dx + A21*dy + A22*dzk;
                float l0 = e0 / det;
                float l1 = e1 / det;
                float l2 = e2 / det;
                float l3 = 1.0f - (l0 + l1 + l2);
                bool inside = (l0 >= 0.0f) & (l0 <= 1.0f) &
                              (l1 >= 0.0f) & (l1 <= 1.0f) &
                              (l2 >= 0.0f) & (l2 <= 1.0f) &
                              (l3 >= 0.0f) & (l3 <= 1.0f);
                if (needex & inside) fnd |= (1u << k);
            }
            if (def) fnd |= (1u << k);
            if (k < 3) { n0 += ss0; n1 += ss1; n2 += ss2; sm += sss; }
        }
    };

    // pairwise candidate loop over one mask word; true => all lanes done
    auto processWord = [&](unsigned long long m, int base) -> bool {
        while (m) {
            int b0 = __builtin_ctzll(m); m &= m - 1;
            int f0 = __builtin_amdgcn_readfirstlane(base + b0);
            const float* bo0 = bb + f0 * RECF;
            if (m) {
                int b1 = __builtin_ctzll(m); m &= m - 1;
                int f1 = __builtin_amdgcn_readfirstlane(base + b1);
                const float* bo1 = bb + f1 * RECF;
                process(bo0);
                process(bo1);
            } else {
                process(bo0);
            }
            if (__all(fnd == 15u)) return true;
        }
        return false;
    };

    // hoist all 8 mask words (independent s_loads issue together)
    unsigned long long m0 = mp[0], m1 = mp[1], m2 = mp[2], m3 = mp[3];
    unsigned long long m4 = mp[4], m5 = mp[5], m6 = mp[6], m7 = mp[7];
    if (processWord(m0,   0)) goto done;
    if (processWord(m1,  64)) goto done;
    if (processWord(m2, 128)) goto done;
    if (processWord(m3, 192)) goto done;
    if (processWord(m4, 256)) goto done;
    if (processWord(m5, 320)) goto done;
    if (processWord(m6, 384)) goto done;
    if (processWord(m7, 448)) goto done;
done:
    {
        float4 v;
        v.x = (fnd & 1u) ? 1.0f : 0.0f;
        v.y = (fnd & 2u) ? 1.0f : 0.0f;
        v.z = (fnd & 4u) ? 1.0f : 0.0f;
        v.w = (fnd & 8u) ? 1.0f : 0.0f;
        *(float4*)&out[(size_t)b*(VWD*VWD*VWD) + (size_t)ix*(VWD*VWD) + iy*VWD + iz0] = v;
    }
}

extern "C" void kernel_launch(void* const* d_in, const int* in_sizes, int n_in,
                              void* d_out, int out_size, void* d_ws, size_t ws_size,
                              hipStream_t stream) {
    const float* vertices = (const float*)d_in[0];   // (8, 2048, 3) f32
    const int*   facets   = (const int*)d_in[1];     // (8, 512, 4) int
    float*       out      = (float*)d_out;           // (8, 96, 96, 96) f32

    // d_ws layout: cul SoA (352 KB) | body (320 KB) | masks (1.77 MB)
    float* cul  = (float*)d_ws;
    float* body = (float*)((char*)d_ws + (size_t)CULC * NBATCH * NFAC * 4);
    unsigned long long* msk =
        (unsigned long long*)((char*)d_ws +
                              (size_t)(CULC + RECF) * NBATCH * NFAC * 4);

    precompute_kernel<<<NBATCH, 512, 0, stream>>>(vertices, facets, cul, body);
    mask_kernel<<<dim3(144, NBATCH), 512, 0, stream>>>(cul, msk);
    dim3 grid(NSLAB / 4, NBATCH);   // 864 blocks * 4 waves = 3456 slabs/batch
    voxelize_kernel<<<grid, 256, 0, stream>>>(body, msk, out);
}

// Round 11
// 145.813 us; speedup vs baseline: 1.0465x; 1.0465x over previous
//
#include <hip/hip_runtime.h>

// Match numpy f32 semantics: no FMA contraction anywhere in this TU.
#pragma clang fp contract(off)

#define VWD 96
#define NVERT 2048
#define NFAC 512
#define NBATCH 8
#define NSLAB 3456          // 12 x 12 x 24 slabs of 8x8x4 voxels
#define RECF 16             // floats per facet body record (AoS, scalar-loaded)
#define CULC 22             // cull components (SoA): bbox 6 + 4 planes x 4

// SoA cull addressing: component c, batch b, facet f
#define CUL(c, b, f) cul[(size_t)(c) * (NBATCH * NFAC) + (size_t)(b) * NFAC + (f)]

// ---------------------------------------------------------------------------
// Kernel 1: per-batch facet precompute, ordered by |det| descending via a
// ONE-BARRIER rank sort. Fully scalarized. Body records SIGN-FOLDED: det<0 =>
// negate A,det (IEEE negation commutes exactly through mul/add/div, so
// n'/det' == n/det bit-for-bit).
//   body[b][s][16] : det, v3x,v3y,v3z, A00..A22, dhi, mhi, pad
//   dhi = det*(1-1e-5) - 1e-25   (definite-inside upper bound on sum)
//   mhi = det*(1+1e-5) + 1e-25   (maybe-inside upper bound; +-1e-25 guards
//                                 det=0 degenerate facets: ref l=NaN=outside)
// ---------------------------------------------------------------------------
__global__ __launch_bounds__(512) void precompute_kernel(
    const float* __restrict__ vertices,
    const int*   __restrict__ facets,
    float*       __restrict__ cul,
    float*       __restrict__ body)
{
    __shared__ unsigned skey[NFAC];
    const int b = blockIdx.x;
    const int j = threadIdx.x;          // one facet per thread
    const float* vb = vertices + (size_t)b * NVERT * 3;

    int4 fi = ((const int4*)facets)[b * NFAC + j];
    float x0 = vb[3*fi.x+0], y0 = vb[3*fi.x+1], z0 = vb[3*fi.x+2];
    float x1 = vb[3*fi.y+0], y1 = vb[3*fi.y+1], z1 = vb[3*fi.y+2];
    float x2 = vb[3*fi.z+0], y2 = vb[3*fi.z+1], z2 = vb[3*fi.z+2];
    float x3 = vb[3*fi.w+0], y3 = vb[3*fi.w+1], z3 = vb[3*fi.w+2];
    float a  = x0-x3, bb = x1-x3, c  = x2-x3;
    float d  = y0-y3, e  = y1-y3, f  = y2-y3;
    float g  = z0-z3, h  = z1-z3, ii = z2-z3;
    float A00 = e*ii - f*h,  A01 = c*h  - bb*ii, A02 = bb*f - c*e;
    float A10 = f*g  - d*ii, A11 = a*ii - c*g,   A12 = c*d  - a*f;
    float A20 = d*h  - e*g,  A21 = bb*g - a*h,   A22 = a*e  - bb*d;
    float det = a*(e*ii - f*h) - bb*(d*ii - f*g) + c*(d*h - e*g);
    if (det < 0.0f) {   // sign-fold (exact)
        det = -det;
        A00 = -A00; A01 = -A01; A02 = -A02;
        A10 = -A10; A11 = -A11; A12 = -A12;
        A20 = -A20; A21 = -A21; A22 = -A22;
    }
    unsigned myk = ~__float_as_uint(det);   // ascending key == descending |det|
    skey[j] = myk;
    __syncthreads();

    // rank = #{k : key_k < myk or (key_k == myk and k < j)}  -> unique slot
    int rank = 0;
    const uint4* sk4 = (const uint4*)skey;
    for (int k0 = 0; k0 < NFAC; k0 += 4) {
        uint4 kk = sk4[k0 >> 2];
        rank += (kk.x < myk) + ((kk.x == myk) & (k0 + 0 < j));
        rank += (kk.y < myk) + ((kk.y == myk) & (k0 + 1 < j));
        rank += (kk.z < myk) + ((kk.z == myk) & (k0 + 2 < j));
        rank += (kk.w < myk) + ((kk.w == myk) & (k0 + 3 < j));
    }

    CUL(0, b, rank) = fminf(fminf(x0,x1),fminf(x2,x3)) - 1e-4f;
    CUL(1, b, rank) = fminf(fminf(y0,y1),fminf(y2,y3)) - 1e-4f;
    CUL(2, b, rank) = fminf(fminf(z0,z1),fminf(z2,z3)) - 1e-4f;
    CUL(3, b, rank) = fmaxf(fmaxf(x0,x1),fmaxf(x2,x3)) + 1e-4f;
    CUL(4, b, rank) = fmaxf(fmaxf(y0,y1),fmaxf(y2,y3)) + 1e-4f;
    CUL(5, b, rank) = fmaxf(fmaxf(z0,z1),fmaxf(z2,z3)) + 1e-4f;

    // 4 outward face planes, margin-inflated, slab half-extents folded:
    // mask test becomes  dot(n, slab_center) <= rhs  (conservative).
    const float HX = 7.0f/96.0f, HZ = 3.0f/96.0f;
    auto plane = [&](float pax, float pay, float paz,
                     float pbx, float pby, float pbz,
                     float pcx, float pcy, float pcz,
                     float pox, float poy, float poz, int base) {
        float e1x = pbx-pax, e1y = pby-pay, e1z = pbz-paz;
        float e2x = pcx-pax, e2y = pcy-pay, e2z = pcz-paz;
        float nx = e1y*e2z - e1z*e2y;
        float ny = e1z*e2x - e1x*e2z;
        float nz = e1x*e2y - e1y*e2x;
        float sdot = nx*(pox-pax) + ny*(poy-pay) + nz*(poz-paz);
        if (sdot > 0.0f) { nx=-nx; ny=-ny; nz=-nz; sdot=-sdot; }
        float dpl = nx*pax + ny*pay + nz*paz;
        float n1s = fabsf(nx)+fabsf(ny)+fabsf(nz);
        float M = 1e-4f*(-sdot) + 1e-4f*n1s + 1e-4f;
        float rhs = dpl + M + (fabsf(nx)*HX + fabsf(ny)*HX + fabsf(nz)*HZ);
        CUL(base+0, b, rank) = nx;
        CUL(base+1, b, rank) = ny;
        CUL(base+2, b, rank) = nz;
        CUL(base+3, b, rank) = rhs;
    };
    plane(x1,y1,z1, x2,y2,z2, x3,y3,z3, x0,y0,z0, 6);    // opposite v0
    plane(x0,y0,z0, x2,y2,z2, x3,y3,z3, x1,y1,z1, 10);   // opposite v1
    plane(x0,y0,z0, x1,y1,z1, x3,y3,z3, x2,y2,z2, 14);   // opposite v2
    plane(x0,y0,z0, x1,y1,z1, x2,y2,z2, x3,y3,z3, 18);   // opposite v3

    float* bo = body + ((size_t)b * NFAC + rank) * RECF;
    bo[0]  = det; bo[1]  = x3;  bo[2]  = y3;  bo[3]  = z3;
    bo[4]  = A00; bo[5]  = A01; bo[6]  = A02;
    bo[7]  = A10; bo[8]  = A11; bo[9]  = A12;
    bo[10] = A20; bo[11] = A21; bo[12] = A22;
    bo[13] = det * (1.0f - 1e-5f) - 1e-25f;   // dhi
    bo[14] = det * (1.0f + 1e-5f) + 1e-25f;   // mhi
    bo[15] = 0.0f;
}

// ---------------------------------------------------------------------------
// Kernel 2: per-slab 512-bit facet mask. One block per (batch, x-y column);
// facet-per-lane, cull record loaded ONCE (SoA, coalesced), 24 z-slabs via
// incremental plane dots (error ~3e-6 << 1e-4 margin folded into rhs).
// ---------------------------------------------------------------------------
__global__ __launch_bounds__(512) void mask_kernel(
    const float* __restrict__ cul,
    unsigned long long* __restrict__ masks)
{
    const int col = blockIdx.x;           // 0..143 = sx*12+sy
    const int b   = blockIdx.y;
    const int f   = threadIdx.x;          // facet (sorted order)
    const int w   = threadIdx.x >> 6;
    float bminx=CUL(0,b,f), bminy=CUL(1,b,f), bminz=CUL(2,b,f);
    float bmaxx=CUL(3,b,f), bmaxy=CUL(4,b,f), bmaxz=CUL(5,b,f);
    float n0x=CUL(6,b,f),  n0y=CUL(7,b,f),  n0z=CUL(8,b,f),  r0=CUL(9,b,f);
    float n1x=CUL(10,b,f), n1y=CUL(11,b,f), n1z=CUL(12,b,f), r1=CUL(13,b,f);
    float n2x=CUL(14,b,f), n2y=CUL(15,b,f), n2z=CUL(16,b,f), r2=CUL(17,b,f);
    float n3x=CUL(18,b,f), n3y=CUL(19,b,f), n3z=CUL(20,b,f), r3=CUL(21,b,f);

    const int sx = col / 12, sy = col % 12;
    const float cx = (float)(16*sx + 8 - VWD) / 96.0f;
    const float cy = (float)(16*sy + 8 - VWD) / 96.0f;
    const float colminx = (float)(16*sx + 1  - VWD) / 96.0f;
    const float colmaxx = (float)(16*sx + 15 - VWD) / 96.0f;
    const float colminy = (float)(16*sy + 1  - VWD) / 96.0f;
    const float colmaxy = (float)(16*sy + 15 - VWD) / 96.0f;
    const bool ovxy = (bminx <= colmaxx) & (bmaxx >= colminx) &
                      (bminy <= colmaxy) & (bmaxy >= colminy);

    const float cz0   = (float)(4 - VWD) / 96.0f;   // z-center of slab sz=0
    const float stepc = 8.0f / 96.0f;
    float d0 = n0x*cx + n0y*cy + n0z*cz0 - r0;  float s0 = n0z*stepc;
    float d1 = n1x*cx + n1y*cy + n1z*cz0 - r1;  float s1 = n1z*stepc;
    float d2 = n2x*cx + n2y*cy + n2z*cz0 - r2;  float s2 = n2z*stepc;
    float d3 = n3x*cx + n3y*cy + n3z*cz0 - r3;  float s3 = n3z*stepc;
    float zlo = (float)(1 - VWD) / 96.0f;
    float zhi = (float)(7 - VWD) / 96.0f;

    unsigned long long* mp = masks + ((size_t)b * NSLAB + (size_t)col * 24) * 8 + w;
#pragma unroll 4
    for (int sz = 0; sz < 24; ++sz) {
        bool ov = ovxy & (bminz <= zhi) & (bmaxz >= zlo) &
                  (d0 <= 0.0f) & (d1 <= 0.0f) & (d2 <= 0.0f) & (d3 <= 0.0f);
        unsigned long long bal = __ballot((int)ov);
        if ((threadIdx.x & 63) == 0) mp[(size_t)sz * 8] = bal;
        d0 += s0; d1 += s1; d2 += s2; d3 += s3;
        zlo += stepc; zhi += stepc;
    }
}

// ---------------------------------------------------------------------------
// Kernel 3: one wave per 8x8x4 slab (4 z-voxels/lane). Per candidate, the
// numerators n_i^k are computed BIT-IDENTICAL to the reference for every k:
// p_i = fl(fl(A_i0*dx)+fl(A_i1*dy)) cached, n_i^k = fl(p_i + fl(A_i2*dz_k)).
// Hence l_i >= 0 <=> n_i >= 0 EXACTLY (division is sign-exact, det>0 after
// sign-fold); only the sum/upper bound carries a shell:
//   def = (min3(n)>=0) & (sm <= dhi)  => ref-inside   [proof: n_i <= sum <=
//         sm(1+2.5e-7) <= det(1-1e-5)(1+2.5e-7) < det => l_i <= 1; s =
//         fl(fl(l0+l1)+l2) <= (sum/det)(1+4e-7) < 1 => l3 >= 0]
//   ref-inside => (min3(n)>=0) & (sm <= mhi)          [sum <= det(1+7e-7)]
// Shell width det*2e-5 (14x safety) => exact path (3 IEEE divisions) fires
// ~2% of candidates instead of ~70% with the old 1e-3 absolute margin.
// ---------------------------------------------------------------------------
__global__ __launch_bounds__(256) void voxelize_kernel(
    const float*              __restrict__ body,
    const unsigned long long* __restrict__ masks,
    float*                    __restrict__ out)
{
    const int b    = blockIdx.y;
    const int wave = threadIdx.x >> 6;
    const int lane = threadIdx.x & 63;
    const int slab = blockIdx.x * 4 + wave;          // 0 .. 3455
    const int sz = slab % 24;
    const int sy = (slab / 24) % 12;
    const int sx = slab / 288;
    const int ix  = sx*8 + (lane >> 3);
    const int iy  = sy*8 + (lane & 7);
    const int iz0 = sz*4;

    const float px  = (float)(2*ix + 1 - VWD) / 96.0f;
    const float py  = (float)(2*iy + 1 - VWD) / 96.0f;
    // wave-uniform z coords of the slab's 4 voxel planes (ref-exact)
    const float pz0 = (float)(2*(iz0+0) + 1 - VWD) / 96.0f;
    const float pz1 = (float)(2*(iz0+1) + 1 - VWD) / 96.0f;
    const float pz2 = (float)(2*(iz0+2) + 1 - VWD) / 96.0f;
    const float pz3 = (float)(2*(iz0+3) + 1 - VWD) / 96.0f;

    const unsigned long long* mp = masks + ((size_t)b * NSLAB + slab) * 8;
    const float* bb = body + (size_t)b * NFAC * RECF;

    unsigned fnd = 0u;   // bit k = voxel (ix,iy,iz0+k) found
    for (int w = 0; w < 8; ++w) {
        unsigned long long m = mp[w];   // wave-uniform -> SGPR
        while (m) {
            int bit = __builtin_ctzll(m);
            m &= m - 1;
            int f = __builtin_amdgcn_readfirstlane(w * 64 + bit);
            const float* bo = bb + f * RECF;
            float det = bo[0], v3x = bo[1], v3y = bo[2], v3z = bo[3];
            float A00 = bo[4],  A01 = bo[5],  A02 = bo[6];
            float A10 = bo[7],  A11 = bo[8],  A12 = bo[9];
            float A20 = bo[10], A21 = bo[11], A22 = bo[12];
            float dhi = bo[13], mhi = bo[14];
            float dx = px - v3x, dy = py - v3y;
            // ref-exact partials (left-assoc, contract off)
            float p0 = A00*dx + A01*dy;
            float p1 = A10*dx + A11*dy;
            float p2 = A20*dx + A21*dy;
            float dzk0 = pz0 - v3z, dzk1 = pz1 - v3z;
            float dzk2 = pz2 - v3z, dzk3 = pz3 - v3z;
#pragma unroll
            for (int k = 0; k < 4; ++k) {
                float dzk = (k == 0) ? dzk0 : (k == 1) ? dzk1
                          : (k == 2) ? dzk2 : dzk3;
                // n_i bit-identical to reference's numerators
                float n0 = p0 + A02*dzk;
                float n1 = p1 + A12*dzk;
                float n2 = p2 + A22*dzk;
                float sm = (n0 + n1) + n2;
                float mn = fminf(fminf(n0, n1), n2);   // v_min3_f32
                bool ge0 = (mn >= 0.0f);               // EXACT l_i>=0 test
                bool def = ge0 & (sm <= dhi);
                bool may = ge0 & (sm <= mhi);
                bool needex = may & !def & !((fnd >> k) & 1u);
                if (__any(needex)) {
                    // exact path (rare): n_i are already ref-exact, so just
                    // the ref's divisions and final test
                    float l0 = n0 / det;
                    float l1 = n1 / det;
                    float l2 = n2 / det;
                    float l3 = 1.0f - ((l0 + l1) + l2);
                    bool inside = (l0 >= 0.0f) & (l0 <= 1.0f) &
                                  (l1 >= 0.0f) & (l1 <= 1.0f) &
                                  (l2 >= 0.0f) & (l2 <= 1.0f) &
                                  (l3 >= 0.0f) & (l3 <= 1.0f);
                    if (needex & inside) fnd |= (1u << k);
                }
                if (def) fnd |= (1u << k);
            }
            if (__all(fnd == 15u)) goto done;
        }
    }
done:
    float4 v;
    v.x = (fnd & 1u) ? 1.0f : 0.0f;
    v.y = (fnd & 2u) ? 1.0f : 0.0f;
    v.z = (fnd & 4u) ? 1.0f : 0.0f;
    v.w = (fnd & 8u) ? 1.0f : 0.0f;
    *(float4*)&out[(size_t)b*(VWD*VWD*VWD) + (size_t)ix*(VWD*VWD) + iy*VWD + iz0] = v;
}

extern "C" void kernel_launch(void* const* d_in, const int* in_sizes, int n_in,
                              void* d_out, int out_size, void* d_ws, size_t ws_size,
                              hipStream_t stream) {
    const float* vertices = (const float*)d_in[0];   // (8, 2048, 3) f32
    const int*   facets   = (const int*)d_in[1];     // (8, 512, 4) int
    float*       out      = (float*)d_out;           // (8, 96, 96, 96) f32

    // d_ws layout: cul SoA (352 KB) | body (256 KB) | masks (1.77 MB)
    float* cul  = (float*)d_ws;
    float* body = (float*)((char*)d_ws + (size_t)CULC * NBATCH * NFAC * 4);
    unsigned long long* msk =
        (unsigned long long*)((char*)d_ws +
                              (size_t)(CULC + RECF) * NBATCH * NFAC * 4);

    precompute_kernel<<<NBATCH, 512, 0, stream>>>(vertices, facets, cul, body);
    mask_kernel<<<dim3(144, NBATCH), 512, 0, stream>>>(cul, msk);
    dim3 grid(NSLAB / 4, NBATCH);   // 864 blocks * 4 waves = 3456 slabs/batch
    voxelize_kernel<<<grid, 256, 0, stream>>>(body, msk, out);
}